// Round 1
// baseline (26826.471 us; speedup 1.0000x reference)
//
#include <hip/hip_runtime.h>
#include <hip/hip_bf16.h>
#include <math.h>

#define T_LEN 1500
#define DM 256
#define DI 64
#define MEMN 10
#define NS 32
#define SYNCD 528
#define VOC 15
#define MINWN 16

typedef _Float16 f16x2 __attribute__((ext_vector_type(2)));
typedef _Float16 f16x8 __attribute__((ext_vector_type(8)));

#if __has_builtin(__builtin_amdgcn_fdot2)
#define FDOT2(a, b, c) __builtin_amdgcn_fdot2((a), (b), (c), false)
#else
static __device__ inline float fdot2_sw(f16x2 a, f16x2 b, float c) {
  return c + (float)a.x * (float)b.x + (float)a.y * (float)b.y;
}
#define FDOT2(a, b, c) fdot2_sw((a), (b), (c))
#endif

static __device__ inline f16x2 pack2(float a, float b) {
  f16x2 r; r.x = (_Float16)a; r.y = (_Float16)b; return r;
}

static __device__ inline float sigm(float x) { return 1.0f / (1.0f + __expf(-x)); }

struct Params {
  const float *x, *st0, *ast0, *Wb, *bb, *Wf, *bf, *gf, *bef,
              *Wd, *bd, *gd, *bed, *Wu, *bu, *gu, *beu, *gs, *bes,
              *w1, *b1, *w2, *b2, *Wh, *bh;
  float* out;
};

struct Smem {
  float Wb[DI * DI];            // [k*64 + j]
  float W1[4 * MEMN * DM];      // [(h*10+m)*256 + d]  (transposed for conflict-free d-major reads)
  float W2[4 * DM];             // [(hp*2+u)*256 + d]
  float B1[4 * DM];             // [h*256 + d]
  float B2[2 * DM];             // [u*256 + d]
  float Bf[2 * DM];
  float Bu[2 * DM];
  float Bd[2 * MINWN];
  float Gf[DM], Bef[DM], Gu[DM], Beu[DM], Gs[DM], Bes[DM];
  float Gd[MINWN], Bed[MINWN];
  float Bh[VOC + 1];
  float Bb[DI];
  float St[MEMN * DM];          // circular: slot s holds a state; logical m = (head+m)%10
  float H0[DM];
  float Act[DM];
  float D1[MINWN];
  float Kv[DI];
  float X2[2][DI];
  __attribute__((aligned(16))) f16x2 Pre2[160];
  float Partial[2 * 512];
  float Prod[SYNCD];
  float RedA[8], RedB[8];
  int Pair[SYNCD];
};

__global__ __launch_bounds__(512, 2) void ctm_kernel(Params P) {
  const int tid = threadIdx.x;
  const int b = blockIdx.x;
  extern __shared__ char smraw[];
  Smem* sm = (Smem*)smraw;

  // ---------------- preload LDS (once) ----------------
  for (int i = tid; i < DI * DI; i += 512) sm->Wb[i] = P.Wb[i];
  for (int i = tid; i < 4 * MEMN * DM; i += 512) {
    int h = i / (MEMN * DM);
    int m = (i / DM) % MEMN;
    int d = i % DM;
    sm->W1[i] = P.w1[(m * DM + d) * 4 + h];
  }
  for (int i = tid; i < 4 * DM; i += 512) {
    int hp = i >> 9, u = (i >> 8) & 1, d = i & 255;
    sm->W2[i] = P.w2[(hp * DM + d) * 2 + u];
  }
  for (int i = tid; i < 4 * DM; i += 512) {
    int h = i >> 8, d = i & 255;
    sm->B1[i] = P.b1[d * 4 + h];
  }
  for (int i = tid; i < 2 * DM; i += 512) {
    int u = i >> 8, d = i & 255;
    sm->B2[i] = P.b2[d * 2 + u];
  }
  sm->Bf[tid] = P.bf[tid];
  sm->Bu[tid] = P.bu[tid];
  if (tid < 2 * MINWN) sm->Bd[tid] = P.bd[tid];
  if (tid < DM) {
    sm->Gf[tid] = P.gf[tid];  sm->Bef[tid] = P.bef[tid];
    sm->Gu[tid] = P.gu[tid];  sm->Beu[tid] = P.beu[tid];
    sm->Gs[tid] = P.gs[tid];  sm->Bes[tid] = P.bes[tid];
  }
  if (tid < MINWN) { sm->Gd[tid] = P.gd[tid]; sm->Bed[tid] = P.bed[tid]; }
  if (tid < VOC) sm->Bh[tid] = P.bh[tid];
  if (tid < DI) sm->Bb[tid] = P.bb[tid];
  for (int i = tid; i < MEMN * DM; i += 512) {
    int m = i / DM, d = i % DM;
    sm->St[i] = P.st0[d * MEMN + m];
  }
  if (tid < DM) sm->Act[tid] = P.ast0[tid * MEMN + (MEMN - 1)];
  if (tid < DI) sm->X2[0][tid] = P.x[(size_t)(b * T_LEN + 0) * DI + tid];
  for (int p = tid; p < SYNCD; p += 512) {
    int i = 0, cum = 0;
    while (p >= cum + (NS - i)) { cum += NS - i; ++i; }
    sm->Pair[p] = (i << 8) | (i + (p - cum));
  }

  // ---------------- per-thread register weights ----------------
  const int kq = tid >> 8;       // K-split half: 0 or 1 (K range kq*160..+160)
  const int c2 = tid & 255;      // owns output cols c2 (a) and c2+256 (b)
  f16x2 wf[2][80];
  #pragma unroll
  for (int j = 0; j < 2; ++j) {
    int col = c2 + 256 * j;
    #pragma unroll
    for (int kk = 0; kk < 80; ++kk) {
      int k = kq * 160 + 2 * kk;
      wf[j][kk] = pack2(P.Wf[(size_t)k * 512 + col], P.Wf[(size_t)(k + 1) * 512 + col]);
    }
  }
  const int jD = tid & 31, kcD = tid >> 5;   // Wd: (col j, 16-wide K chunk)
  float wd[16];
  #pragma unroll
  for (int q = 0; q < 16; ++q) wd[q] = P.Wd[(kcD * 16 + q) * 32 + jD];
  float wu[16];
  #pragma unroll
  for (int k = 0; k < 16; ++k) wu[k] = P.Wu[k * 512 + tid];

  int head = 0;
  __syncthreads();

  // ---------------- time loop ----------------
  for (int t = 0; t < T_LEN; ++t) {
    // prefetch next timestep's features into registers (hidden under step work)
    float xr = 0.f;
    if (tid < DI && t + 1 < T_LEN) xr = P.x[(size_t)(b * T_LEN + t + 1) * DI + tid];
    const float* sX = sm->X2[t & 1];

    // kv = relu(x @ Wb + bb)
    {
      int j = tid & 63, kc = tid >> 6;
      float s = 0.f;
      #pragma unroll
      for (int q = 0; q < 8; ++q) s += sX[kc * 8 + q] * sm->Wb[(kc * 8 + q) * 64 + j];
      sm->Partial[kc * 64 + j] = s;
    }
    __syncthreads();
    if (tid < DI) {
      float v = sm->Bb[tid];
      #pragma unroll
      for (int kc = 0; kc < 8; ++kc) v += sm->Partial[kc * 64 + tid];
      sm->Kv[tid] = fmaxf(v, 0.f);
    }
    __syncthreads();

    for (int it = 0; it < 2; ++it) {
      // pack pre = [kv, act] to f16 pairs
      if (tid < 160) {
        int i0 = 2 * tid, i1 = 2 * tid + 1;
        float lo = (i0 < DI) ? sm->Kv[i0] : sm->Act[i0 - DI];
        float hi = (i1 < DI) ? sm->Kv[i1] : sm->Act[i1 - DI];
        sm->Pre2[tid] = pack2(lo, hi);
      }
      __syncthreads();

      // Wf GEMV: pre(320) @ Wf(320x512), register-resident f16 weights, v_dot2
      {
        float a0 = 0.f, a1 = 0.f;
        const f16x8* pr8 = (const f16x8*)&sm->Pre2[kq * 80];
        #pragma unroll
        for (int kb8 = 0; kb8 < 20; ++kb8) {
          f16x8 pp = pr8[kb8];
          #pragma unroll
          for (int e = 0; e < 4; ++e) {
            f16x2 p; p.x = pp[2 * e]; p.y = pp[2 * e + 1];
            a0 = FDOT2(wf[0][kb8 * 4 + e], p, a0);
            a1 = FDOT2(wf[1][kb8 * 4 + e], p, a1);
          }
        }
        sm->Partial[kq * 512 + c2] = a0;
        sm->Partial[kq * 512 + 256 + c2] = a1;
      }
      __syncthreads();

      // GLU + LN -> h0
      float g = 0.f;
      if (tid < DM) {
        float a  = sm->Partial[tid] + sm->Partial[512 + tid] + sm->Bf[tid];
        float bb_ = sm->Partial[256 + tid] + sm->Partial[512 + 256 + tid] + sm->Bf[256 + tid];
        g = a * sigm(bb_);
        float s1 = g, s2 = g * g;
        #pragma unroll
        for (int m = 32; m >= 1; m >>= 1) { s1 += __shfl_xor(s1, m); s2 += __shfl_xor(s2, m); }
        if ((tid & 63) == 0) { sm->RedA[tid >> 6] = s1; sm->RedB[tid >> 6] = s2; }
      }
      __syncthreads();
      float h0v = 0.f;
      if (tid < DM) {
        float S1 = sm->RedA[0] + sm->RedA[1] + sm->RedA[2] + sm->RedA[3];
        float S2 = sm->RedB[0] + sm->RedB[1] + sm->RedB[2] + sm->RedB[3];
        float mean = S1 * (1.f / 256.f);
        float var = S2 * (1.f / 256.f) - mean * mean;
        h0v = (g - mean) * rsqrtf(var + 1e-5f) * sm->Gf[tid] + sm->Bef[tid];
        sm->H0[tid] = h0v;
      }
      __syncthreads();

      // Wd: h0(256) -> 32, GLU+LN -> d1(16)
      {
        float s = 0.f;
        #pragma unroll
        for (int q = 0; q < 16; ++q) s += sm->H0[kcD * 16 + q] * wd[q];
        sm->Partial[kcD * 32 + jD] = s;
      }
      __syncthreads();
      if (tid < 64) {
        int jj = tid & 15;
        float a = sm->Bd[jj], bb_ = sm->Bd[16 + jj];
        #pragma unroll
        for (int kc = 0; kc < 16; ++kc) {
          a   += sm->Partial[kc * 32 + jj];
          bb_ += sm->Partial[kc * 32 + 16 + jj];
        }
        float gg = a * sigm(bb_);
        float s1 = gg, s2 = gg * gg;
        #pragma unroll
        for (int m = 8; m >= 1; m >>= 1) { s1 += __shfl_xor(s1, m); s2 += __shfl_xor(s2, m); }
        float mean = s1 * (1.f / 16.f);
        float var = s2 * (1.f / 16.f) - mean * mean;
        float d1 = (gg - mean) * rsqrtf(var + 1e-5f) * sm->Gd[jj] + sm->Bed[jj];
        if (tid < MINWN) sm->D1[tid] = d1;
      }
      __syncthreads();

      // Wu: d1(16) -> 512 (register weights, full-K per thread)
      {
        float acc = sm->Bu[tid];
        #pragma unroll
        for (int k = 0; k < 16; ++k) acc += sm->D1[k] * wu[k];
        sm->Partial[tid] = acc;
      }
      __syncthreads();

      // GLU + LN -> u0; then state = LN(u0 + h0)
      float gu_ = 0.f;
      if (tid < DM) {
        float a = sm->Partial[tid], bb_ = sm->Partial[256 + tid];
        gu_ = a * sigm(bb_);
        float s1 = gu_, s2 = gu_ * gu_;
        #pragma unroll
        for (int m = 32; m >= 1; m >>= 1) { s1 += __shfl_xor(s1, m); s2 += __shfl_xor(s2, m); }
        if ((tid & 63) == 0) { sm->RedA[tid >> 6] = s1; sm->RedB[tid >> 6] = s2; }
      }
      __syncthreads();
      float x2v = 0.f;
      if (tid < DM) {
        float S1 = sm->RedA[0] + sm->RedA[1] + sm->RedA[2] + sm->RedA[3];
        float S2 = sm->RedB[0] + sm->RedB[1] + sm->RedB[2] + sm->RedB[3];
        float mean = S1 * (1.f / 256.f);
        float var = S2 * (1.f / 256.f) - mean * mean;
        float u0 = (gu_ - mean) * rsqrtf(var + 1e-5f) * sm->Gu[tid] + sm->Beu[tid];
        x2v = u0 + h0v;
        float s1 = x2v, s2 = x2v * x2v;
        #pragma unroll
        for (int m = 32; m >= 1; m >>= 1) { s1 += __shfl_xor(s1, m); s2 += __shfl_xor(s2, m); }
        if ((tid & 63) == 0) { sm->RedA[4 + (tid >> 6)] = s1; sm->RedB[4 + (tid >> 6)] = s2; }
      }
      __syncthreads();
      if (tid < DM) {
        float S1 = sm->RedA[4] + sm->RedA[5] + sm->RedA[6] + sm->RedA[7];
        float S2 = sm->RedB[4] + sm->RedB[5] + sm->RedB[6] + sm->RedB[7];
        float mean = S1 * (1.f / 256.f);
        float var = S2 * (1.f / 256.f) - mean * mean;
        float state = (x2v - mean) * rsqrtf(var + 1e-5f) * sm->Gs[tid] + sm->Bes[tid];
        sm->St[head * DM + tid] = state;   // overwrite oldest slot
      }
      __syncthreads();
      head = head + 1; if (head >= MEMN) head = 0;

      // nlm: per-channel tiny MLP over trace FIFO -> act
      if (tid < DM) {
        float h1[4];
        #pragma unroll
        for (int h = 0; h < 4; ++h) h1[h] = sm->B1[h * DM + tid];
        #pragma unroll
        for (int m = 0; m < MEMN; ++m) {
          int slot = head + m; if (slot >= MEMN) slot -= MEMN;
          float tr = sm->St[slot * DM + tid];
          #pragma unroll
          for (int h = 0; h < 4; ++h) h1[h] += tr * sm->W1[(h * MEMN + m) * DM + tid];
        }
        float g0 = h1[0] * sigm(h1[2]);
        float g1 = h1[1] * sigm(h1[3]);
        float o0 = g0 * sm->W2[0 * DM + tid] + g1 * sm->W2[2 * DM + tid] + sm->B2[0 * DM + tid];
        float o1 = g0 * sm->W2[1 * DM + tid] + g1 * sm->W2[3 * DM + tid] + sm->B2[1 * DM + tid];
        sm->Act[tid] = o0 * sigm(o1);
      }
      __syncthreads();
    } // it

    // sync representation: outer-product upper triangle of act[:32]
    {
      int pr = sm->Pair[tid];
      sm->Prod[tid] = sm->Act[pr >> 8] * sm->Act[pr & 255];
      if (tid < SYNCD - 512) {
        int pr2 = sm->Pair[512 + tid];
        sm->Prod[512 + tid] = sm->Act[pr2 >> 8] * sm->Act[pr2 & 255];
      }
    }
    __syncthreads();
    if (tid < 240) {
      int kc = tid / 15, v = tid - kc * 15;
      float s = 0.f;
      #pragma unroll
      for (int q = 0; q < 33; ++q) {
        int p = kc * 33 + q;
        s += sm->Prod[p] * P.Wh[p * 15 + v];
      }
      sm->Partial[kc * 15 + v] = s;
    }
    __syncthreads();
    if (tid < VOC) {
      float o = sm->Bh[tid];
      #pragma unroll
      for (int kc = 0; kc < 16; ++kc) o += sm->Partial[kc * 15 + tid];
      P.out[(size_t)(b * T_LEN + t) * VOC + tid] = o;
    }
    if (tid < DI) sm->X2[(t + 1) & 1][tid] = xr;  // commit prefetched x
    __syncthreads();
  } // t
}

extern "C" void kernel_launch(void* const* d_in, const int* in_sizes, int n_in,
                              void* d_out, int out_size, void* d_ws, size_t ws_size,
                              hipStream_t stream) {
  Params P;
  P.x   = (const float*)d_in[0];
  P.st0 = (const float*)d_in[1];
  P.ast0= (const float*)d_in[2];
  P.Wb  = (const float*)d_in[3];
  P.bb  = (const float*)d_in[4];
  P.Wf  = (const float*)d_in[5];
  P.bf  = (const float*)d_in[6];
  P.gf  = (const float*)d_in[7];
  P.bef = (const float*)d_in[8];
  P.Wd  = (const float*)d_in[9];
  P.bd  = (const float*)d_in[10];
  P.gd  = (const float*)d_in[11];
  P.bed = (const float*)d_in[12];
  P.Wu  = (const float*)d_in[13];
  P.bu  = (const float*)d_in[14];
  P.gu  = (const float*)d_in[15];
  P.beu = (const float*)d_in[16];
  P.gs  = (const float*)d_in[17];
  P.bes = (const float*)d_in[18];
  P.w1  = (const float*)d_in[19];
  P.b1  = (const float*)d_in[20];
  P.w2  = (const float*)d_in[21];
  P.b2  = (const float*)d_in[22];
  P.Wh  = (const float*)d_in[23];
  P.bh  = (const float*)d_in[24];
  P.out = (float*)d_out;

  int B = in_sizes[0] / (T_LEN * DI);
  hipLaunchKernelGGL(ctm_kernel, dim3(B), dim3(512), sizeof(Smem), stream, P);
}

// Round 2
// 14413.562 us; speedup vs baseline: 1.8612x; 1.8612x over previous
//
#include <hip/hip_runtime.h>
#include <math.h>

#define T_LEN 1500
#define DM 256
#define DI 64
#define MEMN 10
#define SYNCD 528
#define VOC 15

typedef _Float16 f16x2 __attribute__((ext_vector_type(2)));
typedef _Float16 f16x8 __attribute__((ext_vector_type(8)));

#define FDOT2(a, b, c) __builtin_amdgcn_fdot2((a), (b), (c), false)

static __device__ __forceinline__ float dot8(f16x8 w, f16x8 q, float acc) {
  acc = FDOT2(__builtin_shufflevector(w, w, 0, 1), __builtin_shufflevector(q, q, 0, 1), acc);
  acc = FDOT2(__builtin_shufflevector(w, w, 2, 3), __builtin_shufflevector(q, q, 2, 3), acc);
  acc = FDOT2(__builtin_shufflevector(w, w, 4, 5), __builtin_shufflevector(q, q, 4, 5), acc);
  acc = FDOT2(__builtin_shufflevector(w, w, 6, 7), __builtin_shufflevector(q, q, 6, 7), acc);
  return acc;
}
static __device__ __forceinline__ f16x2 pack2(float a, float b) {
  f16x2 r; r.x = (_Float16)a; r.y = (_Float16)b; return r;
}
static __device__ __forceinline__ float sigm(float x) { return 1.0f / (1.0f + __expf(-x)); }

struct Params {
  const float *x, *st0, *ast0, *Wb, *bb, *Wf, *bf, *gf, *bef,
              *Wd, *bd, *gd, *bed, *Wu, *bu, *gu, *beu, *gs, *bes,
              *w1, *b1, *w2, *b2, *Wh, *bh;
  float* out;
};

struct Smem {
  float4 W1v[MEMN * DM];        // [m*256+d] = w1[m][d][0..3]
  float4 W2v[DM];               // [d] = {w2[0][d][0], w2[0][d][1], w2[1][d][0], w2[1][d][1]}
  float4 B1v[DM];
  float2 B2v[DM];
  float Bf[2 * DM];
  float Bu[2 * DM];
  float Bd[32];
  float Gf[DM], Bef[DM], Gu[DM], Beu[DM], Gs[DM], Bes[DM];
  float Gd[16], Bed[16];
  float Bh[16];
  float Bb[DI];
  __attribute__((aligned(16))) float St[MEMN * DM];   // slot-major circular trace
  __attribute__((aligned(16))) float H0[DM];
  float Act[DM];
  __attribute__((aligned(16))) float D1[16];
  float X2[2][DI];
  __attribute__((aligned(16))) f16x2 Pre2[160];       // [0..31]=kv f16 pairs, [32..159]=act pairs
  float PartD[16 * 33];         // Wd partials, stride 33 (conflict-free read)
  float PartK[512];             // Wb partials
  float PartH[240];             // Wh partials (16 chunks x 15 vocab)
  float2 RedAB[8];
  float2 Red2AB[8];
  float Prod[SYNCD];
  float WhL[SYNCD * VOC];
  int Pair[SYNCD];
};

#define FOR20(X) X(0) X(1) X(2) X(3) X(4) X(5) X(6) X(7) X(8) X(9) \
                 X(10) X(11) X(12) X(13) X(14) X(15) X(16) X(17) X(18) X(19)

#define DECLW(i) f16x8 wa##i, wb##i;
#define LOADW(i) { const float* Wc = P.Wf + (size_t)(p160 + (i) * 8) * 512 + ch; \
  f16x8 ta, tb; \
  _Pragma("unroll") for (int e = 0; e < 8; ++e) { \
    ta[e] = (_Float16)Wc[e * 512]; tb[e] = (_Float16)Wc[e * 512 + 256]; } \
  wa##i = ta; wb##i = tb; }
#define DOT0(i) { f16x8 q = pr8[i]; aA0 = dot8(wa##i, q, aA0); aB0 = dot8(wb##i, q, aB0); }
#define DOT1(i) { f16x8 q = pr8[i]; aA1 = dot8(wa##i, q, aA1); aB1 = dot8(wb##i, q, aB1); }
#define DOTSEQ DOT0(0) DOT1(1) DOT0(2) DOT1(3) DOT0(4) DOT1(5) DOT0(6) DOT1(7) DOT0(8) DOT1(9) \
               DOT0(10) DOT1(11) DOT0(12) DOT1(13) DOT0(14) DOT1(15) DOT0(16) DOT1(17) DOT0(18) DOT1(19)

__global__ __launch_bounds__(512, 2) __attribute__((amdgpu_waves_per_eu(2, 2)))
void ctm_kernel(Params P) {
  const int tid = threadIdx.x;
  const int b = blockIdx.x;
  extern __shared__ char smraw[];
  Smem* sm = (Smem*)smraw;

  // ---------------- LDS preload (once) ----------------
  for (int i = tid; i < MEMN * DM; i += 512) sm->W1v[i] = ((const float4*)P.w1)[i];
  if (tid < DM) {
    float2 a = ((const float2*)P.w2)[tid];
    float2 c = ((const float2*)P.w2)[DM + tid];
    float4 w; w.x = a.x; w.y = a.y; w.z = c.x; w.w = c.y;
    sm->W2v[tid] = w;
    sm->B1v[tid] = ((const float4*)P.b1)[tid];
    sm->B2v[tid] = ((const float2*)P.b2)[tid];
    sm->Gf[tid] = P.gf[tid]; sm->Bef[tid] = P.bef[tid];
    sm->Gu[tid] = P.gu[tid]; sm->Beu[tid] = P.beu[tid];
    sm->Gs[tid] = P.gs[tid]; sm->Bes[tid] = P.bes[tid];
  }
  sm->Bf[tid] = P.bf[tid];
  sm->Bu[tid] = P.bu[tid];
  if (tid < 32) sm->Bd[tid] = P.bd[tid];
  if (tid < 16) { sm->Gd[tid] = P.gd[tid]; sm->Bed[tid] = P.bed[tid]; }
  if (tid < VOC) sm->Bh[tid] = P.bh[tid];
  if (tid < DI) sm->Bb[tid] = P.bb[tid];
  for (int i = tid; i < MEMN * DM; i += 512) {
    int m = i >> 8, d = i & 255;
    sm->St[m * DM + d] = P.st0[d * MEMN + m];
  }
  if (tid < DI) sm->X2[0][tid] = P.x[(size_t)b * T_LEN * DI + tid];
  for (int i = tid; i < SYNCD * VOC; i += 512) sm->WhL[i] = P.Wh[i];
  for (int pp = tid; pp < SYNCD; pp += 512) {
    int i = 0, cum = 0;
    while (pp >= cum + (32 - i)) { cum += 32 - i; ++i; }
    sm->Pair[pp] = (i << 8) | (i + (pp - cum));
  }

  // ---------------- register-resident weights ----------------
  const int p = tid & 1;         // K-half for Wf/Wu; parity pairing for a/b columns
  const int ch = tid >> 1;       // owned channel 0..255
  const int p160 = p * 160;
  FOR20(DECLW)
  FOR20(LOADW)
  const int jD = tid & 31, kcD = tid >> 5;   // Wd: (col, 16-wide K chunk)
  float wd[16];
  #pragma unroll
  for (int q = 0; q < 16; ++q) wd[q] = P.Wd[(kcD * 16 + q) * 32 + jD];
  float wua[8], wub[8];
  #pragma unroll
  for (int q = 0; q < 8; ++q) {
    wua[q] = P.Wu[(p * 8 + q) * 512 + ch];
    wub[q] = P.Wu[(p * 8 + q) * 512 + ch + 256];
  }
  const int jK = tid & 63, kcK = tid >> 6;   // Wb: (col, 8-wide K chunk)
  float wbr[8];
  #pragma unroll
  for (int q = 0; q < 8; ++q) wbr[q] = P.Wb[(kcK * 8 + q) * 64 + jK];

  __syncthreads();

  // ---------------- prologue: kv(t=0) + initial act pack ----------------
  {
    float s = 0.f;
    #pragma unroll
    for (int q = 0; q < 8; ++q) s += sm->X2[0][kcK * 8 + q] * wbr[q];
    sm->PartK[kcK * 64 + jK] = s;
    if ((tid & 3) == 0) {
      int e = tid >> 2;
      float a0 = P.ast0[(2 * e) * MEMN + (MEMN - 1)];
      float a1 = P.ast0[(2 * e + 1) * MEMN + (MEMN - 1)];
      sm->Pre2[32 + e] = pack2(a0, a1);
    }
  }
  __syncthreads();
  if (tid >= 256 && tid < 320) {
    int j = tid - 256;
    float kv = sm->Bb[j];
    #pragma unroll
    for (int kc = 0; kc < 8; ++kc) kv += sm->PartK[kc * 64 + j];
    kv = fmaxf(kv, 0.f);
    float kn = __shfl_xor(kv, 1);
    if ((j & 1) == 0) sm->Pre2[j >> 1] = pack2(kv, kn);
  }
  __syncthreads();

  int head = 0;
  // ---------------- time loop ----------------
  for (int t = 0; t < T_LEN; ++t) {
    float xr = 0.f;
    if (tid < DI && t + 1 < T_LEN) xr = P.x[((size_t)b * T_LEN + (t + 1)) * DI + tid];

    for (int it = 0; it < 2; ++it) {
      // ---- P1: Wf GEMV (even/odd K-split, a/b col pair) + GLU + wave-reduce ----
      if (it == 1 && tid < DI) sm->X2[(t + 1) & 1][tid] = xr;
      float aA0 = 0.f, aA1 = 0.f, aB0 = 0.f, aB1 = 0.f;
      const f16x8* pr8 = (const f16x8*)(sm->Pre2 + p * 80);
      DOTSEQ
      float av = aA0 + aA1, bv = aB0 + aB1;
      av += __shfl_xor(av, 1); bv += __shfl_xor(bv, 1);
      av += sm->Bf[ch]; bv += sm->Bf[DM + ch];
      float g = av * sigm(bv);
      float s1 = g, s2 = g * g;
      #pragma unroll
      for (int m = 1; m < 64; m <<= 1) { s1 += __shfl_xor(s1, m); s2 += __shfl_xor(s2, m); }
      if ((tid & 63) == 0) { float2 r; r.x = s1; r.y = s2; sm->RedAB[tid >> 6] = r; }
      __syncthreads();  // B1

      // ---- P2: h0 = LN(g) ----
      float S1 = 0.f, S2 = 0.f;
      #pragma unroll
      for (int w = 0; w < 8; ++w) { float2 r = sm->RedAB[w]; S1 += r.x; S2 += r.y; }
      float mean = S1 * (1.0f / 512.0f);            // both-lane redundant => 2*sum/512
      float var = S2 * (1.0f / 512.0f) - mean * mean;
      float h0v = (g - mean) * rsqrtf(var + 1e-5f) * sm->Gf[ch] + sm->Bef[ch];
      if (!p) sm->H0[ch] = h0v;
      __syncthreads();  // B2

      // ---- P3: Wd partials ----
      {
        float s = 0.f;
        #pragma unroll
        for (int qq = 0; qq < 4; ++qq) {
          float4 hv = ((const float4*)sm->H0)[kcD * 4 + qq];
          s += hv.x * wd[qq * 4 + 0] + hv.y * wd[qq * 4 + 1]
             + hv.z * wd[qq * 4 + 2] + hv.w * wd[qq * 4 + 3];
        }
        sm->PartD[kcD * 33 + jD] = s;
      }
      __syncthreads();  // B3

      // ---- P4: d1 = LN(GLU(Wd out)) (wave 0 only) ----
      if (tid < 32) {
        int j = tid & 15;
        int half = tid >> 4;
        float s = 0.f;
        #pragma unroll
        for (int kc = 0; kc < 16; ++kc) s += sm->PartD[kc * 33 + half * 16 + j];
        float oth = __shfl_xor(s, 16);
        float gg = (s + sm->Bd[j]) * sigm(oth + sm->Bd[16 + j]);
        float t1 = gg, t2 = gg * gg;
        #pragma unroll
        for (int m = 1; m < 16; m <<= 1) { t1 += __shfl_xor(t1, m); t2 += __shfl_xor(t2, m); }
        float mn = t1 * (1.0f / 16.0f), vr = t2 * (1.0f / 16.0f) - mn * mn;
        float d1 = (gg - mn) * rsqrtf(vr + 1e-5f) * sm->Gd[j] + sm->Bed[j];
        if (tid < 16) sm->D1[j] = d1;
      }
      __syncthreads();  // B4

      // ---- P5: Wu (K-split by parity) + GLU + wave-reduce ----
      float gu;
      {
        const float4* d4 = (const float4*)sm->D1;
        float4 dl = d4[p * 2], dh = d4[p * 2 + 1];
        float ua = dl.x * wua[0] + dl.y * wua[1] + dl.z * wua[2] + dl.w * wua[3]
                 + dh.x * wua[4] + dh.y * wua[5] + dh.z * wua[6] + dh.w * wua[7];
        float ub = dl.x * wub[0] + dl.y * wub[1] + dl.z * wub[2] + dl.w * wub[3]
                 + dh.x * wub[4] + dh.y * wub[5] + dh.z * wub[6] + dh.w * wub[7];
        ua += __shfl_xor(ua, 1); ub += __shfl_xor(ub, 1);
        ua += sm->Bu[ch]; ub += sm->Bu[DM + ch];
        gu = ua * sigm(ub);
        float t1 = gu, t2 = gu * gu;
        #pragma unroll
        for (int m = 1; m < 64; m <<= 1) { t1 += __shfl_xor(t1, m); t2 += __shfl_xor(t2, m); }
        if ((tid & 63) == 0) { float2 r; r.x = t1; r.y = t2; sm->RedAB[tid >> 6] = r; }
      }
      __syncthreads();  // B5

      // ---- P6: u0 = LN(gu); x2 = u0 + h0; reduce for state-LN ----
      float x2v;
      {
        float U1 = 0.f, U2 = 0.f;
        #pragma unroll
        for (int w = 0; w < 8; ++w) { float2 r = sm->RedAB[w]; U1 += r.x; U2 += r.y; }
        float mn = U1 * (1.0f / 512.0f), vr = U2 * (1.0f / 512.0f) - mn * mn;
        float u0 = (gu - mn) * rsqrtf(vr + 1e-5f) * sm->Gu[ch] + sm->Beu[ch];
        x2v = u0 + h0v;
        float t1 = x2v, t2 = x2v * x2v;
        #pragma unroll
        for (int m = 1; m < 64; m <<= 1) { t1 += __shfl_xor(t1, m); t2 += __shfl_xor(t2, m); }
        if ((tid & 63) == 0) { float2 r; r.x = t1; r.y = t2; sm->Red2AB[tid >> 6] = r; }
      }
      __syncthreads();  // B6

      // ---- P7: state = LN(x2); trace update; nlm -> act; pack pre ----
      {
        float V1 = 0.f, V2 = 0.f;
        #pragma unroll
        for (int w = 0; w < 8; ++w) { float2 r = sm->Red2AB[w]; V1 += r.x; V2 += r.y; }
        float mn = V1 * (1.0f / 512.0f), vr = V2 * (1.0f / 512.0f) - mn * mn;
        float state = (x2v - mn) * rsqrtf(vr + 1e-5f) * sm->Gs[ch] + sm->Bes[ch];
        if (!p) sm->St[head * DM + ch] = state;
        float4 h1 = sm->B1v[ch];
        int base = head + 1; if (base >= MEMN) base -= MEMN;
        #pragma unroll
        for (int m = 0; m < MEMN - 1; ++m) {
          int slot = base + m; if (slot >= MEMN) slot -= MEMN;
          float tr = sm->St[slot * DM + ch];
          float4 wv = sm->W1v[m * DM + ch];
          h1.x += tr * wv.x; h1.y += tr * wv.y; h1.z += tr * wv.z; h1.w += tr * wv.w;
        }
        {
          float4 wv = sm->W1v[(MEMN - 1) * DM + ch];
          h1.x += state * wv.x; h1.y += state * wv.y; h1.z += state * wv.z; h1.w += state * wv.w;
        }
        float g0 = h1.x * sigm(h1.z), g1 = h1.y * sigm(h1.w);
        float4 w2v = sm->W2v[ch];
        float2 b2v = sm->B2v[ch];
        float o0 = g0 * w2v.x + g1 * w2v.z + b2v.x;
        float o1 = g0 * w2v.y + g1 * w2v.w + b2v.y;
        float act = o0 * sigm(o1);
        if (!p) sm->Act[ch] = act;
        float an = __shfl_xor(act, 2);
        if ((tid & 3) == 0) sm->Pre2[32 + (tid >> 2)] = pack2(act, an);
        head += 1; if (head >= MEMN) head = 0;
      }
      __syncthreads();  // B7
    }  // it

    // ---- S1: sync products + next-step Wb partials + store logits(t-1) ----
    {
      int pr = sm->Pair[tid];
      sm->Prod[tid] = sm->Act[pr >> 8] * sm->Act[pr & 255];
      if (tid < SYNCD - 512) {
        int pr2 = sm->Pair[512 + tid];
        sm->Prod[512 + tid] = sm->Act[pr2 >> 8] * sm->Act[pr2 & 255];
      }
      const float* X = sm->X2[(t + 1) & 1];
      float s = 0.f;
      #pragma unroll
      for (int q = 0; q < 8; ++q) s += X[kcK * 8 + q] * wbr[q];
      sm->PartK[kcK * 64 + jK] = s;
      if (t > 0 && tid < VOC) {
        float o = sm->Bh[tid];
        #pragma unroll
        for (int kc2 = 0; kc2 < 16; ++kc2) o += sm->PartH[kc2 * 15 + tid];
        P.out[((size_t)b * T_LEN + (t - 1)) * VOC + tid] = o;
      }
    }
    __syncthreads();  // B8

    // ---- S2: Wh partials + kv reduce/pack for t+1 ----
    if (tid < 240) {
      int kc = (tid * 4370) >> 16;
      int v = tid - kc * 15;
      float s = 0.f;
      #pragma unroll
      for (int q = 0; q < 33; ++q) {
        int pp = kc * 33 + q;
        s += sm->Prod[pp] * sm->WhL[pp * 15 + v];
      }
      sm->PartH[kc * 15 + v] = s;
    } else if (tid >= 256 && tid < 320) {
      int j = tid - 256;
      float kv = sm->Bb[j];
      #pragma unroll
      for (int kc = 0; kc < 8; ++kc) kv += sm->PartK[kc * 64 + j];
      kv = fmaxf(kv, 0.f);
      float kn = __shfl_xor(kv, 1);
      if ((j & 1) == 0) sm->Pre2[j >> 1] = pack2(kv, kn);
    }
    __syncthreads();  // B9
  }  // t

  // epilogue: logits for t = T-1
  if (tid < VOC) {
    float o = sm->Bh[tid];
    #pragma unroll
    for (int kc = 0; kc < 16; ++kc) o += sm->PartH[kc * 15 + tid];
    P.out[((size_t)b * T_LEN + (T_LEN - 1)) * VOC + tid] = o;
  }
}

extern "C" void kernel_launch(void* const* d_in, const int* in_sizes, int n_in,
                              void* d_out, int out_size, void* d_ws, size_t ws_size,
                              hipStream_t stream) {
  (void)d_ws; (void)ws_size; (void)n_in; (void)out_size;
  Params P;
  P.x   = (const float*)d_in[0];
  P.st0 = (const float*)d_in[1];
  P.ast0= (const float*)d_in[2];
  P.Wb  = (const float*)d_in[3];
  P.bb  = (const float*)d_in[4];
  P.Wf  = (const float*)d_in[5];
  P.bf  = (const float*)d_in[6];
  P.gf  = (const float*)d_in[7];
  P.bef = (const float*)d_in[8];
  P.Wd  = (const float*)d_in[9];
  P.bd  = (const float*)d_in[10];
  P.gd  = (const float*)d_in[11];
  P.bed = (const float*)d_in[12];
  P.Wu  = (const float*)d_in[13];
  P.bu  = (const float*)d_in[14];
  P.gu  = (const float*)d_in[15];
  P.beu = (const float*)d_in[16];
  P.gs  = (const float*)d_in[17];
  P.bes = (const float*)d_in[18];
  P.w1  = (const float*)d_in[19];
  P.b1  = (const float*)d_in[20];
  P.w2  = (const float*)d_in[21];
  P.b2  = (const float*)d_in[22];
  P.Wh  = (const float*)d_in[23];
  P.bh  = (const float*)d_in[24];
  P.out = (float*)d_out;

  int B = in_sizes[0] / (T_LEN * DI);
  hipFuncSetAttribute((const void*)ctm_kernel, hipFuncAttributeMaxDynamicSharedMemorySize,
                      (int)sizeof(Smem));
  hipLaunchKernelGGL(ctm_kernel, dim3(B), dim3(512), sizeof(Smem), stream, P);
}

// Round 3
// 14412.062 us; speedup vs baseline: 1.8614x; 1.0001x over previous
//
#include <hip/hip_runtime.h>
#include <math.h>

#define T_LEN 1500
#define DM 256
#define DI 64
#define MEMN 10
#define SYNCD 528
#define VOC 15

typedef _Float16 f16x2 __attribute__((ext_vector_type(2)));
typedef _Float16 f16x8 __attribute__((ext_vector_type(8)));

#define FDOT2(a, b, c) __builtin_amdgcn_fdot2((a), (b), (c), false)

static __device__ __forceinline__ float dot8(f16x8 w, f16x8 q, float acc) {
  acc = FDOT2(__builtin_shufflevector(w, w, 0, 1), __builtin_shufflevector(q, q, 0, 1), acc);
  acc = FDOT2(__builtin_shufflevector(w, w, 2, 3), __builtin_shufflevector(q, q, 2, 3), acc);
  acc = FDOT2(__builtin_shufflevector(w, w, 4, 5), __builtin_shufflevector(q, q, 4, 5), acc);
  acc = FDOT2(__builtin_shufflevector(w, w, 6, 7), __builtin_shufflevector(q, q, 6, 7), acc);
  return acc;
}
static __device__ __forceinline__ f16x2 pack2(float a, float b) {
  f16x2 r; r.x = (_Float16)a; r.y = (_Float16)b; return r;
}
static __device__ __forceinline__ float sigm(float x) { return 1.0f / (1.0f + __expf(-x)); }

struct Params {
  const float *x, *st0, *ast0, *Wb, *bb, *Wf, *bf, *gf, *bef,
              *Wd, *bd, *gd, *bed, *Wu, *bu, *gu, *beu, *gs, *bes,
              *w1, *b1, *w2, *b2, *Wh, *bh;
  float* out;
};

struct Smem {
  float4 W1v[MEMN * DM];        // [m*256+d] = w1[m][d][0..3]
  float4 W2v[DM];               // [d] = {w2[0][d][0], w2[0][d][1], w2[1][d][0], w2[1][d][1]}
  float4 B1v[DM];
  float2 B2v[DM];
  float Bf[2 * DM];
  float Bu[2 * DM];
  float Bd[32];
  float Gf[DM], Bef[DM], Gu[DM], Beu[DM], Gs[DM], Bes[DM];
  float Gd[16], Bed[16];
  float Bh[16];
  float Bb[DI];
  __attribute__((aligned(16))) float St[MEMN * DM];   // slot-major circular trace
  __attribute__((aligned(16))) float H0[DM];
  float Act[DM];
  __attribute__((aligned(16))) float D1[16];
  float X2[2][DI];
  __attribute__((aligned(16))) f16x2 Pre2[160];       // [0..31]=kv f16 pairs, [32..159]=act pairs
  float PartD[16 * 33];         // Wd partials, stride 33 (conflict-free read)
  float PartK[512];             // Wb partials
  float PartH[240];             // Wh partials (16 chunks x 15 vocab)
  float2 RedAB[8];
  float2 Red2AB[8];
  float Prod[SYNCD];
  float WhL[SYNCD * VOC];
  int Pair[SYNCD];
};

#define FOR20(X) X(0) X(1) X(2) X(3) X(4) X(5) X(6) X(7) X(8) X(9) \
                 X(10) X(11) X(12) X(13) X(14) X(15) X(16) X(17) X(18) X(19)

#define DECLW(i) f16x8 wa##i, wb##i;
#define LOADW(i) { const float* Wc = P.Wf + (size_t)(p160 + (i) * 8) * 512 + ch; \
  f16x8 ta, tb; \
  _Pragma("unroll") for (int e = 0; e < 8; ++e) { \
    ta[e] = (_Float16)Wc[e * 512]; tb[e] = (_Float16)Wc[e * 512 + 256]; } \
  wa##i = ta; wb##i = tb; }
#define DOT0(i) { f16x8 q = pr8[i]; aA0 = dot8(wa##i, q, aA0); aB0 = dot8(wb##i, q, aB0); }
#define DOT1(i) { f16x8 q = pr8[i]; aA1 = dot8(wa##i, q, aA1); aB1 = dot8(wb##i, q, aB1); }
#define DOTSEQ DOT0(0) DOT1(1) DOT0(2) DOT1(3) DOT0(4) DOT1(5) DOT0(6) DOT1(7) DOT0(8) DOT1(9) \
               DOT0(10) DOT1(11) DOT0(12) DOT1(13) DOT0(14) DOT1(15) DOT0(16) DOT1(17) DOT0(18) DOT1(19)

__global__ __launch_bounds__(512) __attribute__((amdgpu_waves_per_eu(1, 2)))
void ctm_kernel(Params P) {
  const int tid = threadIdx.x;
  const int b = blockIdx.x;
  extern __shared__ char smraw[];
  Smem* sm = (Smem*)smraw;

  // ---------------- LDS preload (once) ----------------
  for (int i = tid; i < MEMN * DM; i += 512) sm->W1v[i] = ((const float4*)P.w1)[i];
  if (tid < DM) {
    float2 a = ((const float2*)P.w2)[tid];
    float2 c = ((const float2*)P.w2)[DM + tid];
    float4 w; w.x = a.x; w.y = a.y; w.z = c.x; w.w = c.y;
    sm->W2v[tid] = w;
    sm->B1v[tid] = ((const float4*)P.b1)[tid];
    sm->B2v[tid] = ((const float2*)P.b2)[tid];
    sm->Gf[tid] = P.gf[tid]; sm->Bef[tid] = P.bef[tid];
    sm->Gu[tid] = P.gu[tid]; sm->Beu[tid] = P.beu[tid];
    sm->Gs[tid] = P.gs[tid]; sm->Bes[tid] = P.bes[tid];
  }
  sm->Bf[tid] = P.bf[tid];
  sm->Bu[tid] = P.bu[tid];
  if (tid < 32) sm->Bd[tid] = P.bd[tid];
  if (tid < 16) { sm->Gd[tid] = P.gd[tid]; sm->Bed[tid] = P.bed[tid]; }
  if (tid < VOC) sm->Bh[tid] = P.bh[tid];
  if (tid < DI) sm->Bb[tid] = P.bb[tid];
  for (int i = tid; i < MEMN * DM; i += 512) {
    int m = i >> 8, d = i & 255;
    sm->St[m * DM + d] = P.st0[d * MEMN + m];
  }
  if (tid < DI) sm->X2[0][tid] = P.x[(size_t)b * T_LEN * DI + tid];
  for (int i = tid; i < SYNCD * VOC; i += 512) sm->WhL[i] = P.Wh[i];
  for (int pp = tid; pp < SYNCD; pp += 512) {
    int i = 0, cum = 0;
    while (pp >= cum + (32 - i)) { cum += 32 - i; ++i; }
    sm->Pair[pp] = (i << 8) | (i + (pp - cum));
  }

  // ---------------- register-resident weights ----------------
  const int p = tid & 1;         // K-half for Wf/Wu; parity pairing for a/b columns
  const int ch = tid >> 1;       // owned channel 0..255
  const int p160 = p * 160;
  FOR20(DECLW)
  FOR20(LOADW)
  const int jD = tid & 31, kcD = tid >> 5;   // Wd: (col, 16-wide K chunk)
  float wd[16];
  #pragma unroll
  for (int q = 0; q < 16; ++q) wd[q] = P.Wd[(kcD * 16 + q) * 32 + jD];
  float wua[8], wub[8];
  #pragma unroll
  for (int q = 0; q < 8; ++q) {
    wua[q] = P.Wu[(p * 8 + q) * 512 + ch];
    wub[q] = P.Wu[(p * 8 + q) * 512 + ch + 256];
  }
  const int jK = tid & 63, kcK = tid >> 6;   // Wb: (col, 8-wide K chunk)
  float wbr[8];
  #pragma unroll
  for (int q = 0; q < 8; ++q) wbr[q] = P.Wb[(kcK * 8 + q) * 64 + jK];

  __syncthreads();

  // ---------------- prologue: kv(t=0) + initial act pack ----------------
  {
    float s = 0.f;
    #pragma unroll
    for (int q = 0; q < 8; ++q) s += sm->X2[0][kcK * 8 + q] * wbr[q];
    sm->PartK[kcK * 64 + jK] = s;
    if ((tid & 3) == 0) {
      int e = tid >> 2;
      float a0 = P.ast0[(2 * e) * MEMN + (MEMN - 1)];
      float a1 = P.ast0[(2 * e + 1) * MEMN + (MEMN - 1)];
      sm->Pre2[32 + e] = pack2(a0, a1);
    }
  }
  __syncthreads();
  if (tid >= 256 && tid < 320) {
    int j = tid - 256;
    float kv = sm->Bb[j];
    #pragma unroll
    for (int kc = 0; kc < 8; ++kc) kv += sm->PartK[kc * 64 + j];
    kv = fmaxf(kv, 0.f);
    float kn = __shfl_xor(kv, 1);
    if ((j & 1) == 0) sm->Pre2[j >> 1] = pack2(kv, kn);
  }
  __syncthreads();

  int head = 0;
  // ---------------- time loop ----------------
  for (int t = 0; t < T_LEN; ++t) {
    float xr = 0.f;
    if (tid < DI && t + 1 < T_LEN) xr = P.x[((size_t)b * T_LEN + (t + 1)) * DI + tid];

    for (int it = 0; it < 2; ++it) {
      // ---- P1: Wf GEMV (even/odd K-split, a/b col pair) + GLU + wave-reduce ----
      if (it == 1 && tid < DI) sm->X2[(t + 1) & 1][tid] = xr;
      float aA0 = 0.f, aA1 = 0.f, aB0 = 0.f, aB1 = 0.f;
      const f16x8* pr8 = (const f16x8*)(sm->Pre2 + p * 80);
      DOTSEQ
      float av = aA0 + aA1, bv = aB0 + aB1;
      av += __shfl_xor(av, 1); bv += __shfl_xor(bv, 1);
      av += sm->Bf[ch]; bv += sm->Bf[DM + ch];
      float g = av * sigm(bv);
      float s1 = g, s2 = g * g;
      #pragma unroll
      for (int m = 1; m < 64; m <<= 1) { s1 += __shfl_xor(s1, m); s2 += __shfl_xor(s2, m); }
      if ((tid & 63) == 0) { float2 r; r.x = s1; r.y = s2; sm->RedAB[tid >> 6] = r; }
      __syncthreads();  // B1

      // ---- P2: h0 = LN(g) ----
      float S1 = 0.f, S2 = 0.f;
      #pragma unroll
      for (int w = 0; w < 8; ++w) { float2 r = sm->RedAB[w]; S1 += r.x; S2 += r.y; }
      float mean = S1 * (1.0f / 512.0f);            // both-lane redundant => 2*sum/512
      float var = S2 * (1.0f / 512.0f) - mean * mean;
      float h0v = (g - mean) * rsqrtf(var + 1e-5f) * sm->Gf[ch] + sm->Bef[ch];
      if (!p) sm->H0[ch] = h0v;
      __syncthreads();  // B2

      // ---- P3: Wd partials ----
      {
        float s = 0.f;
        #pragma unroll
        for (int qq = 0; qq < 4; ++qq) {
          float4 hv = ((const float4*)sm->H0)[kcD * 4 + qq];
          s += hv.x * wd[qq * 4 + 0] + hv.y * wd[qq * 4 + 1]
             + hv.z * wd[qq * 4 + 2] + hv.w * wd[qq * 4 + 3];
        }
        sm->PartD[kcD * 33 + jD] = s;
      }
      __syncthreads();  // B3

      // ---- P4: d1 = LN(GLU(Wd out)) (wave 0 only) ----
      if (tid < 32) {
        int j = tid & 15;
        int half = tid >> 4;
        float s = 0.f;
        #pragma unroll
        for (int kc = 0; kc < 16; ++kc) s += sm->PartD[kc * 33 + half * 16 + j];
        float oth = __shfl_xor(s, 16);
        float gg = (s + sm->Bd[j]) * sigm(oth + sm->Bd[16 + j]);
        float t1 = gg, t2 = gg * gg;
        #pragma unroll
        for (int m = 1; m < 16; m <<= 1) { t1 += __shfl_xor(t1, m); t2 += __shfl_xor(t2, m); }
        float mn = t1 * (1.0f / 16.0f), vr = t2 * (1.0f / 16.0f) - mn * mn;
        float d1 = (gg - mn) * rsqrtf(vr + 1e-5f) * sm->Gd[j] + sm->Bed[j];
        if (tid < 16) sm->D1[j] = d1;
      }
      __syncthreads();  // B4

      // ---- P5: Wu (K-split by parity) + GLU + wave-reduce ----
      float gu;
      {
        const float4* d4 = (const float4*)sm->D1;
        float4 dl = d4[p * 2], dh = d4[p * 2 + 1];
        float ua = dl.x * wua[0] + dl.y * wua[1] + dl.z * wua[2] + dl.w * wua[3]
                 + dh.x * wua[4] + dh.y * wua[5] + dh.z * wua[6] + dh.w * wua[7];
        float ub = dl.x * wub[0] + dl.y * wub[1] + dl.z * wub[2] + dl.w * wub[3]
                 + dh.x * wub[4] + dh.y * wub[5] + dh.z * wub[6] + dh.w * wub[7];
        ua += __shfl_xor(ua, 1); ub += __shfl_xor(ub, 1);
        ua += sm->Bu[ch]; ub += sm->Bu[DM + ch];
        gu = ua * sigm(ub);
        float t1 = gu, t2 = gu * gu;
        #pragma unroll
        for (int m = 1; m < 64; m <<= 1) { t1 += __shfl_xor(t1, m); t2 += __shfl_xor(t2, m); }
        if ((tid & 63) == 0) { float2 r; r.x = t1; r.y = t2; sm->RedAB[tid >> 6] = r; }
      }
      __syncthreads();  // B5

      // ---- P6: u0 = LN(gu); x2 = u0 + h0; reduce for state-LN ----
      float x2v;
      {
        float U1 = 0.f, U2 = 0.f;
        #pragma unroll
        for (int w = 0; w < 8; ++w) { float2 r = sm->RedAB[w]; U1 += r.x; U2 += r.y; }
        float mn = U1 * (1.0f / 512.0f), vr = U2 * (1.0f / 512.0f) - mn * mn;
        float u0 = (gu - mn) * rsqrtf(vr + 1e-5f) * sm->Gu[ch] + sm->Beu[ch];
        x2v = u0 + h0v;
        float t1 = x2v, t2 = x2v * x2v;
        #pragma unroll
        for (int m = 1; m < 64; m <<= 1) { t1 += __shfl_xor(t1, m); t2 += __shfl_xor(t2, m); }
        if ((tid & 63) == 0) { float2 r; r.x = t1; r.y = t2; sm->Red2AB[tid >> 6] = r; }
      }
      __syncthreads();  // B6

      // ---- P7: state = LN(x2); trace update; nlm -> act; pack pre ----
      {
        float V1 = 0.f, V2 = 0.f;
        #pragma unroll
        for (int w = 0; w < 8; ++w) { float2 r = sm->Red2AB[w]; V1 += r.x; V2 += r.y; }
        float mn = V1 * (1.0f / 512.0f), vr = V2 * (1.0f / 512.0f) - mn * mn;
        float state = (x2v - mn) * rsqrtf(vr + 1e-5f) * sm->Gs[ch] + sm->Bes[ch];
        if (!p) sm->St[head * DM + ch] = state;
        float4 h1 = sm->B1v[ch];
        int base = head + 1; if (base >= MEMN) base -= MEMN;
        #pragma unroll
        for (int m = 0; m < MEMN - 1; ++m) {
          int slot = base + m; if (slot >= MEMN) slot -= MEMN;
          float tr = sm->St[slot * DM + ch];
          float4 wv = sm->W1v[m * DM + ch];
          h1.x += tr * wv.x; h1.y += tr * wv.y; h1.z += tr * wv.z; h1.w += tr * wv.w;
        }
        {
          float4 wv = sm->W1v[(MEMN - 1) * DM + ch];
          h1.x += state * wv.x; h1.y += state * wv.y; h1.z += state * wv.z; h1.w += state * wv.w;
        }
        float g0 = h1.x * sigm(h1.z), g1 = h1.y * sigm(h1.w);
        float4 w2v = sm->W2v[ch];
        float2 b2v = sm->B2v[ch];
        float o0 = g0 * w2v.x + g1 * w2v.z + b2v.x;
        float o1 = g0 * w2v.y + g1 * w2v.w + b2v.y;
        float act = o0 * sigm(o1);
        if (!p) sm->Act[ch] = act;
        float an = __shfl_xor(act, 2);
        if ((tid & 3) == 0) sm->Pre2[32 + (tid >> 2)] = pack2(act, an);
        head += 1; if (head >= MEMN) head = 0;
      }
      __syncthreads();  // B7
    }  // it

    // ---- S1: sync products + next-step Wb partials + store logits(t-1) ----
    {
      int pr = sm->Pair[tid];
      sm->Prod[tid] = sm->Act[pr >> 8] * sm->Act[pr & 255];
      if (tid < SYNCD - 512) {
        int pr2 = sm->Pair[512 + tid];
        sm->Prod[512 + tid] = sm->Act[pr2 >> 8] * sm->Act[pr2 & 255];
      }
      const float* X = sm->X2[(t + 1) & 1];
      float s = 0.f;
      #pragma unroll
      for (int q = 0; q < 8; ++q) s += X[kcK * 8 + q] * wbr[q];
      sm->PartK[kcK * 64 + jK] = s;
      if (t > 0 && tid < VOC) {
        float o = sm->Bh[tid];
        #pragma unroll
        for (int kc2 = 0; kc2 < 16; ++kc2) o += sm->PartH[kc2 * 15 + tid];
        P.out[((size_t)b * T_LEN + (t - 1)) * VOC + tid] = o;
      }
    }
    __syncthreads();  // B8

    // ---- S2: Wh partials + kv reduce/pack for t+1 ----
    if (tid < 240) {
      int kc = (tid * 4370) >> 16;
      int v = tid - kc * 15;
      float s = 0.f;
      #pragma unroll
      for (int q = 0; q < 33; ++q) {
        int pp = kc * 33 + q;
        s += sm->Prod[pp] * sm->WhL[pp * 15 + v];
      }
      sm->PartH[kc * 15 + v] = s;
    } else if (tid >= 256 && tid < 320) {
      int j = tid - 256;
      float kv = sm->Bb[j];
      #pragma unroll
      for (int kc = 0; kc < 8; ++kc) kv += sm->PartK[kc * 64 + j];
      kv = fmaxf(kv, 0.f);
      float kn = __shfl_xor(kv, 1);
      if ((j & 1) == 0) sm->Pre2[j >> 1] = pack2(kv, kn);
    }
    __syncthreads();  // B9
  }  // t

  // epilogue: logits for t = T-1
  if (tid < VOC) {
    float o = sm->Bh[tid];
    #pragma unroll
    for (int kc = 0; kc < 16; ++kc) o += sm->PartH[kc * 15 + tid];
    P.out[((size_t)b * T_LEN + (T_LEN - 1)) * VOC + tid] = o;
  }
}

extern "C" void kernel_launch(void* const* d_in, const int* in_sizes, int n_in,
                              void* d_out, int out_size, void* d_ws, size_t ws_size,
                              hipStream_t stream) {
  (void)d_ws; (void)ws_size; (void)n_in; (void)out_size;
  Params P;
  P.x   = (const float*)d_in[0];
  P.st0 = (const float*)d_in[1];
  P.ast0= (const float*)d_in[2];
  P.Wb  = (const float*)d_in[3];
  P.bb  = (const float*)d_in[4];
  P.Wf  = (const float*)d_in[5];
  P.bf  = (const float*)d_in[6];
  P.gf  = (const float*)d_in[7];
  P.bef = (const float*)d_in[8];
  P.Wd  = (const float*)d_in[9];
  P.bd  = (const float*)d_in[10];
  P.gd  = (const float*)d_in[11];
  P.bed = (const float*)d_in[12];
  P.Wu  = (const float*)d_in[13];
  P.bu  = (const float*)d_in[14];
  P.gu  = (const float*)d_in[15];
  P.beu = (const float*)d_in[16];
  P.gs  = (const float*)d_in[17];
  P.bes = (const float*)d_in[18];
  P.w1  = (const float*)d_in[19];
  P.b1  = (const float*)d_in[20];
  P.w2  = (const float*)d_in[21];
  P.b2  = (const float*)d_in[22];
  P.Wh  = (const float*)d_in[23];
  P.bh  = (const float*)d_in[24];
  P.out = (float*)d_out;

  int B = in_sizes[0] / (T_LEN * DI);
  hipFuncSetAttribute((const void*)ctm_kernel, hipFuncAttributeMaxDynamicSharedMemorySize,
                      (int)sizeof(Smem));
  hipLaunchKernelGGL(ctm_kernel, dim3(B), dim3(512), sizeof(Smem), stream, P);
}